// Round 1
// baseline (802.024 us; speedup 1.0000x reference)
//
#include <hip/hip_runtime.h>
#include <hip/hip_bf16.h>
#include <math.h>

#define NN 50000
#define EE 800000
#define IN_DIM 128
#define H1 8
#define D1 32
#define HID1 256
#define HID2 128
#define FC1 512
#define NEG_SLOPE 0.2f

// ---------------- utility kernels ----------------

__global__ void fill_zero_int(int* p, int n) {
    int i = blockIdx.x * blockDim.x + threadIdx.x;
    if (i < n) p[i] = 0;
}

__global__ void hist_kernel(const int* __restrict__ dst, int* __restrict__ counts) {
    int e = blockIdx.x * blockDim.x + threadIdx.x;
    if (e < EE) atomicAdd(&counts[dst[e]], 1);
}

// single-block exclusive scan over n counts; writes row_ptr[0..n] and cursor[i]=row_ptr[i]
__global__ __launch_bounds__(1024) void scan_kernel(int* __restrict__ counts_cursor,
                                                    int* __restrict__ row_ptr, int n) {
    __shared__ int lds[1024];
    int tid = threadIdx.x;
    int carry = 0;
    int nchunks = (n + 1023) / 1024;
    for (int c = 0; c < nchunks; c++) {
        int idx = c * 1024 + tid;
        int v = (idx < n) ? counts_cursor[idx] : 0;
        lds[tid] = v;
        __syncthreads();
        for (int off = 1; off < 1024; off <<= 1) {
            int t = (tid >= off) ? lds[tid - off] : 0;
            __syncthreads();
            lds[tid] += t;
            __syncthreads();
        }
        int inc = lds[tid];
        int total = lds[1023];
        if (idx < n) {
            int ex = carry + inc - v;
            row_ptr[idx] = ex;
            counts_cursor[idx] = ex;  // cursor
        }
        carry += total;
        __syncthreads();
    }
    if (tid == 0) row_ptr[n] = carry;
}

__global__ void scatter_kernel(const int* __restrict__ src, const int* __restrict__ dst,
                               int* __restrict__ cursor, int* __restrict__ eidx,
                               int* __restrict__ srcs) {
    int e = blockIdx.x * blockDim.x + threadIdx.x;
    if (e >= EE) return;
    int d = dst[e];
    int p = atomicAdd(&cursor[d], 1);
    eidx[p] = e;
    srcs[p] = src[e];
}

// ---------------- GEMM: C[M,Nc] = A[M,K] @ B[K,Nc], fp32, BM=BN=64, BK=16 ----------------

__global__ __launch_bounds__(256) void gemm_kernel(const float* __restrict__ A,
                                                   const float* __restrict__ B,
                                                   float* __restrict__ C,
                                                   int M, int K, int Nc) {
    __shared__ float As[16][65];
    __shared__ float Bs[16][64];
    int bm = blockIdx.x * 64;
    int bn = blockIdx.y * 64;
    int tid = threadIdx.x;
    int tx = tid % 16, ty = tid / 16;
    float c[4][4] = {};
    for (int k0 = 0; k0 < K; k0 += 16) {
        #pragma unroll
        for (int i = 0; i < 4; i++) {
            int m = tid / 16 + i * 16;
            int kk = tid % 16;
            int gm = bm + m;
            As[kk][m] = (gm < M) ? A[(size_t)gm * K + k0 + kk] : 0.f;
        }
        #pragma unroll
        for (int i = 0; i < 4; i++) {
            int kk = tid / 64 + i * 4;
            int j = tid % 64;
            Bs[kk][j] = B[(size_t)(k0 + kk) * Nc + bn + j];
        }
        __syncthreads();
        #pragma unroll
        for (int kk = 0; kk < 16; kk++) {
            float a[4], b[4];
            #pragma unroll
            for (int i = 0; i < 4; i++) a[i] = As[kk][ty * 4 + i];
            #pragma unroll
            for (int j = 0; j < 4; j++) b[j] = Bs[kk][tx * 4 + j];
            #pragma unroll
            for (int i = 0; i < 4; i++)
                #pragma unroll
                for (int j = 0; j < 4; j++) c[i][j] += a[i] * b[j];
        }
        __syncthreads();
    }
    #pragma unroll
    for (int i = 0; i < 4; i++) {
        int gm = bm + ty * 4 + i;
        if (gm >= M) continue;
        #pragma unroll
        for (int j = 0; j < 4; j++)
            C[(size_t)gm * Nc + bn + tx * 4 + j] = c[i][j];
    }
}

// ---------------- layer 1 attention ----------------

__global__ void att1_kernel(const float* __restrict__ h1, const float* __restrict__ att_src,
                            const float* __restrict__ att_dst, float* __restrict__ a_s,
                            float* __restrict__ a_d) {
    int idx = blockIdx.x * blockDim.x + threadIdx.x;
    if (idx >= NN * H1) return;
    int n = idx >> 3, h = idx & 7;
    const float* row = h1 + (size_t)n * HID1 + h * D1;
    float s = 0.f, d = 0.f;
    #pragma unroll
    for (int k = 0; k < D1; k++) {
        float v = row[k];
        s += v * att_src[h * D1 + k];
        d += v * att_dst[h * D1 + k];
    }
    a_s[idx] = s;
    a_d[idx] = d;
}

__global__ void edge_e1_kernel(const int* __restrict__ eidx, const int* __restrict__ srcs,
                               const int* __restrict__ dst, const float* __restrict__ a_s,
                               const float* __restrict__ a_d, float* __restrict__ e1s) {
    int p = blockIdx.x * blockDim.x + threadIdx.x;
    if (p >= EE) return;
    int eid = eidx[p];
    int s = srcs[p];
    int d = dst[eid];
    #pragma unroll
    for (int h = 0; h < H1; h++) {
        float v = a_s[s * H1 + h] + a_d[d * H1 + h];
        e1s[(size_t)p * H1 + h] = (v >= 0.f) ? v : NEG_SLOPE * v;
    }
}

// wave per node: 8 heads x 8 lanes each
__global__ void softmax1_kernel(const int* __restrict__ row_ptr, const int* __restrict__ eidx,
                                float* __restrict__ e1s, float* __restrict__ alpha1_out) {
    int n = blockIdx.x * 4 + (threadIdx.x >> 6);
    int lane = threadIdx.x & 63;
    if (n >= NN) return;
    int start = row_ptr[n], end = row_ptr[n + 1];
    if (start == end) return;
    int h = lane & 7, j = lane >> 3;
    float m = -INFINITY;
    for (int p = start + j; p < end; p += 8) m = fmaxf(m, e1s[(size_t)p * 8 + h]);
    m = fmaxf(m, __shfl_xor(m, 8));
    m = fmaxf(m, __shfl_xor(m, 16));
    m = fmaxf(m, __shfl_xor(m, 32));
    float s = 0.f;
    for (int p = start + j; p < end; p += 8) s += expf(e1s[(size_t)p * 8 + h] - m);
    s += __shfl_xor(s, 8);
    s += __shfl_xor(s, 16);
    s += __shfl_xor(s, 32);
    float inv = 1.f / (s + 1e-16f);
    for (int p = start + j; p < end; p += 8) {
        float a = expf(e1s[(size_t)p * 8 + h] - m) * inv;
        e1s[(size_t)p * 8 + h] = a;
        alpha1_out[(size_t)eidx[p] * 8 + h] = a;
    }
}

__global__ __launch_bounds__(256) void agg1_kernel(const int* __restrict__ row_ptr,
                                                   const int* __restrict__ srcs,
                                                   const float* __restrict__ e1s,
                                                   const float* __restrict__ h1,
                                                   const float* __restrict__ b1,
                                                   float* __restrict__ x1) {
    int n = blockIdx.x;
    int t = threadIdx.x;
    int h = t >> 5;
    int start = row_ptr[n], end = row_ptr[n + 1];
    float acc = 0.f;
    for (int p = start; p < end; p++) {
        float a = e1s[(size_t)p * 8 + h];
        acc += a * h1[(size_t)srcs[p] * HID1 + t];
    }
    acc += b1[t];
    x1[(size_t)n * HID1 + t] = (acc > 0.f) ? acc : expf(acc) - 1.f;  // ELU
}

// ---------------- layer 2 attention (1 head) ----------------

__global__ __launch_bounds__(64) void att2_kernel(const float* __restrict__ h2,
                                                  const float* __restrict__ att_src,
                                                  const float* __restrict__ att_dst,
                                                  float* __restrict__ a_s, float* __restrict__ a_d) {
    int n = blockIdx.x;
    int lane = threadIdx.x;
    const float* row = h2 + (size_t)n * HID2;
    float s = 0.f, d = 0.f;
    for (int k = lane; k < HID2; k += 64) {
        float v = row[k];
        s += v * att_src[k];
        d += v * att_dst[k];
    }
    for (int off = 32; off; off >>= 1) {
        s += __shfl_down(s, off);
        d += __shfl_down(d, off);
    }
    if (lane == 0) {
        a_s[n] = s;
        a_d[n] = d;
    }
}

__global__ void edge_e2_kernel(const int* __restrict__ eidx, const int* __restrict__ srcs,
                               const int* __restrict__ dst, const float* __restrict__ a_s,
                               const float* __restrict__ a_d, float* __restrict__ e2s) {
    int p = blockIdx.x * blockDim.x + threadIdx.x;
    if (p >= EE) return;
    int eid = eidx[p];
    float v = a_s[srcs[p]] + a_d[dst[eid]];
    e2s[p] = (v >= 0.f) ? v : NEG_SLOPE * v;
}

__global__ void softmax2_kernel(const int* __restrict__ row_ptr, const int* __restrict__ eidx,
                                float* __restrict__ e2s, float* __restrict__ alpha2_out) {
    int n = blockIdx.x * 4 + (threadIdx.x >> 6);
    int lane = threadIdx.x & 63;
    if (n >= NN) return;
    int start = row_ptr[n], end = row_ptr[n + 1];
    if (start == end) return;
    float m = -INFINITY;
    for (int p = start + lane; p < end; p += 64) m = fmaxf(m, e2s[p]);
    for (int off = 32; off; off >>= 1) m = fmaxf(m, __shfl_xor(m, off));
    float s = 0.f;
    for (int p = start + lane; p < end; p += 64) s += expf(e2s[p] - m);
    for (int off = 32; off; off >>= 1) s += __shfl_xor(s, off);
    float inv = 1.f / (s + 1e-16f);
    for (int p = start + lane; p < end; p += 64) {
        float a = expf(e2s[p] - m) * inv;
        e2s[p] = a;
        alpha2_out[eidx[p]] = a;
    }
}

__global__ __launch_bounds__(128) void agg2_kernel(const int* __restrict__ row_ptr,
                                                   const int* __restrict__ srcs,
                                                   const float* __restrict__ e2s,
                                                   const float* __restrict__ h2,
                                                   const float* __restrict__ b2,
                                                   float* __restrict__ x2) {
    int n = blockIdx.x;
    int t = threadIdx.x;
    int start = row_ptr[n], end = row_ptr[n + 1];
    float acc = 0.f;
    for (int p = start; p < end; p++) acc += e2s[p] * h2[(size_t)srcs[p] * HID2 + t];
    acc += b2[t];
    x2[(size_t)n * HID2 + t] = (acc > 0.f) ? acc : 0.f;  // ReLU
}

// ---------------- fused FC head: 8 nodes per block of 512 threads ----------------

#define NT 8
__global__ __launch_bounds__(512) void fc_kernel(const float* __restrict__ x2,
                                                 const float* __restrict__ fcW1,
                                                 const float* __restrict__ fcb1,
                                                 const float* __restrict__ fcW2,
                                                 const float* __restrict__ fcb2,
                                                 float* __restrict__ out) {
    __shared__ float xs[NT][HID2];
    __shared__ float red[NT][8];
    int n0 = blockIdx.x * NT;
    int tid = threadIdx.x;
    for (int i = tid; i < NT * HID2; i += 512) {
        int ni = i >> 7;
        int d = i & 127;
        int gn = n0 + ni;
        xs[ni][d] = (gn < NN) ? x2[(size_t)gn * HID2 + d] : 0.f;
    }
    __syncthreads();
    int k = tid;  // 0..511
    float hv[NT] = {};
    for (int d = 0; d < HID2; d++) {
        float w = fcW1[d * FC1 + k];
        #pragma unroll
        for (int i = 0; i < NT; i++) hv[i] += xs[i][d] * w;
    }
    float b = fcb1[k], w2 = fcW2[k];
    #pragma unroll
    for (int i = 0; i < NT; i++) {
        float hh = hv[i] + b;
        hv[i] = ((hh > 0.f) ? hh : 0.f) * w2;
    }
    int wave = tid >> 6, lane = tid & 63;
    #pragma unroll
    for (int i = 0; i < NT; i++) {
        float v = hv[i];
        for (int off = 32; off; off >>= 1) v += __shfl_down(v, off);
        if (lane == 0) red[i][wave] = v;
    }
    __syncthreads();
    if (tid < NT) {
        float s = fcb2[0];
        #pragma unroll
        for (int w = 0; w < 8; w++) s += red[tid][w];
        int gn = n0 + tid;
        if (gn < NN) out[gn] = s;
    }
}

// ---------------- host launch ----------------

extern "C" void kernel_launch(void* const* d_in, const int* in_sizes, int n_in,
                              void* d_out, int out_size, void* d_ws, size_t ws_size,
                              hipStream_t stream) {
    (void)in_sizes; (void)n_in; (void)out_size; (void)ws_size;
    const float* x        = (const float*)d_in[0];
    const int*   eindex   = (const int*)d_in[1];
    const float* W1       = (const float*)d_in[2];
    const float* att_src1 = (const float*)d_in[3];
    const float* att_dst1 = (const float*)d_in[4];
    const float* b1       = (const float*)d_in[5];
    const float* W2       = (const float*)d_in[6];
    const float* att_src2 = (const float*)d_in[7];
    const float* att_dst2 = (const float*)d_in[8];
    const float* b2       = (const float*)d_in[9];
    const float* fcW1     = (const float*)d_in[10];
    const float* fcb1     = (const float*)d_in[11];
    const float* fcW2     = (const float*)d_in[12];
    const float* fcb2     = (const float*)d_in[13];

    const int* src = eindex;
    const int* dst = eindex + EE;

    float* out_n      = (float*)d_out;             // [N]
    float* alpha1_out = out_n + NN;                // [E,8]
    float* alpha2_out = alpha1_out + (size_t)EE * 8; // [E]

    // workspace layout (aligned 256B)
    char* ws = (char*)d_ws;
    size_t off = 0;
    auto alloc = [&](size_t bytes) {
        size_t o = off;
        off = (off + bytes + 255) & ~(size_t)255;
        return o;
    };
    size_t o_rowptr = alloc((NN + 1) * sizeof(int));
    size_t o_cursor = alloc(NN * sizeof(int));
    size_t o_eidx   = alloc(EE * sizeof(int));
    size_t o_srcs   = alloc(EE * sizeof(int));
    size_t o_h1     = alloc((size_t)NN * HID1 * sizeof(float)); // reused: h2 (first half), x2 (second half)
    size_t o_x1     = alloc((size_t)NN * HID1 * sizeof(float));
    size_t o_e1s    = alloc((size_t)EE * H1 * sizeof(float));   // reused: e2s
    size_t o_as1    = alloc((size_t)NN * H1 * sizeof(float));   // reused: a_s2
    size_t o_ad1    = alloc((size_t)NN * H1 * sizeof(float));   // reused: a_d2

    int*   row_ptr = (int*)(ws + o_rowptr);
    int*   cursor  = (int*)(ws + o_cursor);
    int*   eidx    = (int*)(ws + o_eidx);
    int*   srcs    = (int*)(ws + o_srcs);
    float* h1      = (float*)(ws + o_h1);
    float* x1      = (float*)(ws + o_x1);
    float* e1s     = (float*)(ws + o_e1s);
    float* a_s1    = (float*)(ws + o_as1);
    float* a_d1    = (float*)(ws + o_ad1);
    // aliases for layer 2
    float* h2   = h1;                                   // [N,128]
    float* x2   = h1 + (size_t)NN * HID2;               // [N,128]
    float* e2s  = e1s;                                  // [E]
    float* a_s2 = a_s1;                                 // [N]
    float* a_d2 = a_d1;                                 // [N]

    // ---- build CSR by dst ----
    fill_zero_int<<<(NN + 255) / 256, 256, 0, stream>>>(cursor, NN);
    hist_kernel<<<(EE + 255) / 256, 256, 0, stream>>>(dst, cursor);
    scan_kernel<<<1, 1024, 0, stream>>>(cursor, row_ptr, NN);
    scatter_kernel<<<(EE + 255) / 256, 256, 0, stream>>>(src, dst, cursor, eidx, srcs);

    // ---- layer 1 ----
    gemm_kernel<<<dim3((NN + 63) / 64, HID1 / 64), 256, 0, stream>>>(x, W1, h1, NN, IN_DIM, HID1);
    att1_kernel<<<(NN * H1 + 255) / 256, 256, 0, stream>>>(h1, att_src1, att_dst1, a_s1, a_d1);
    edge_e1_kernel<<<(EE + 255) / 256, 256, 0, stream>>>(eidx, srcs, dst, a_s1, a_d1, e1s);
    softmax1_kernel<<<(NN + 3) / 4, 256, 0, stream>>>(row_ptr, eidx, e1s, alpha1_out);
    agg1_kernel<<<NN, 256, 0, stream>>>(row_ptr, srcs, e1s, h1, b1, x1);

    // ---- layer 2 ----
    gemm_kernel<<<dim3((NN + 63) / 64, HID2 / 64), 256, 0, stream>>>(x1, W2, h2, NN, HID1, HID2);
    att2_kernel<<<NN, 64, 0, stream>>>(h2, att_src2, att_dst2, a_s2, a_d2);
    edge_e2_kernel<<<(EE + 255) / 256, 256, 0, stream>>>(eidx, srcs, dst, a_s2, a_d2, e2s);
    softmax2_kernel<<<(NN + 3) / 4, 256, 0, stream>>>(row_ptr, eidx, e2s, alpha2_out);
    agg2_kernel<<<NN, 128, 0, stream>>>(row_ptr, srcs, e2s, h2, b2, x2);

    // ---- FC head ----
    fc_kernel<<<(NN + NT - 1) / NT, 512, 0, stream>>>(x2, fcW1, fcb1, fcW2, fcb2, out_n);
}

// Round 2
// 691.719 us; speedup vs baseline: 1.1595x; 1.1595x over previous
//
#include <hip/hip_runtime.h>
#include <hip/hip_bf16.h>
#include <math.h>

#define NN 50000
#define EE 800000
#define IN_DIM 128
#define H1 8
#define D1 32
#define HID1 256
#define HID2 128
#define FC1 512
#define NEG_SLOPE 0.2f

__device__ __forceinline__ float bf2f(unsigned short u) {
    unsigned int x = ((unsigned int)u) << 16;
    return __uint_as_float(x);
}

// ---------------- utility kernels ----------------

__global__ void fill_zero_int(int* p, int n) {
    int i = blockIdx.x * blockDim.x + threadIdx.x;
    if (i < n) p[i] = 0;
}

__global__ void hist_kernel(const int* __restrict__ dst, int* __restrict__ counts) {
    int e = blockIdx.x * blockDim.x + threadIdx.x;
    if (e < EE) atomicAdd(&counts[dst[e]], 1);
}

// single-block exclusive scan over n counts; writes row_ptr[0..n] and cursor[i]=row_ptr[i]
__global__ __launch_bounds__(1024) void scan_kernel(int* __restrict__ counts_cursor,
                                                    int* __restrict__ row_ptr, int n) {
    __shared__ int lds[1024];
    int tid = threadIdx.x;
    int carry = 0;
    int nchunks = (n + 1023) / 1024;
    for (int c = 0; c < nchunks; c++) {
        int idx = c * 1024 + tid;
        int v = (idx < n) ? counts_cursor[idx] : 0;
        lds[tid] = v;
        __syncthreads();
        for (int off = 1; off < 1024; off <<= 1) {
            int t = (tid >= off) ? lds[tid - off] : 0;
            __syncthreads();
            lds[tid] += t;
            __syncthreads();
        }
        int inc = lds[tid];
        int total = lds[1023];
        if (idx < n) {
            int ex = carry + inc - v;
            row_ptr[idx] = ex;
            counts_cursor[idx] = ex;  // cursor
        }
        carry += total;
        __syncthreads();
    }
    if (tid == 0) row_ptr[n] = carry;
}

__global__ void scatter_kernel(const int* __restrict__ src, const int* __restrict__ dst,
                               int* __restrict__ cursor, int* __restrict__ eidx,
                               int* __restrict__ srcs) {
    int e = blockIdx.x * blockDim.x + threadIdx.x;
    if (e >= EE) return;
    int d = dst[e];
    int p = atomicAdd(&cursor[d], 1);
    eidx[p] = e;
    srcs[p] = src[e];
}

// ---------------- GEMM: C[M,Nc] = A[M,K] @ B[K,Nc], fp32, BM=BN=64, BK=16 ----------------
// Also writes a bf16 copy of C when Cbf != nullptr (for the gather-side aggregations).

__global__ __launch_bounds__(256) void gemm_kernel(const float* __restrict__ A,
                                                   const float* __restrict__ B,
                                                   float* __restrict__ C,
                                                   __hip_bfloat16* __restrict__ Cbf,
                                                   int M, int K, int Nc) {
    __shared__ float As[16][65];
    __shared__ float Bs[16][64];
    int bm = blockIdx.x * 64;
    int bn = blockIdx.y * 64;
    int tid = threadIdx.x;
    int tx = tid % 16, ty = tid / 16;
    float c[4][4] = {};
    for (int k0 = 0; k0 < K; k0 += 16) {
        #pragma unroll
        for (int i = 0; i < 4; i++) {
            int m = tid / 16 + i * 16;
            int kk = tid % 16;
            int gm = bm + m;
            As[kk][m] = (gm < M) ? A[(size_t)gm * K + k0 + kk] : 0.f;
        }
        #pragma unroll
        for (int i = 0; i < 4; i++) {
            int kk = tid / 64 + i * 4;
            int j = tid % 64;
            Bs[kk][j] = B[(size_t)(k0 + kk) * Nc + bn + j];
        }
        __syncthreads();
        #pragma unroll
        for (int kk = 0; kk < 16; kk++) {
            float a[4], b[4];
            #pragma unroll
            for (int i = 0; i < 4; i++) a[i] = As[kk][ty * 4 + i];
            #pragma unroll
            for (int j = 0; j < 4; j++) b[j] = Bs[kk][tx * 4 + j];
            #pragma unroll
            for (int i = 0; i < 4; i++)
                #pragma unroll
                for (int j = 0; j < 4; j++) c[i][j] += a[i] * b[j];
        }
        __syncthreads();
    }
    #pragma unroll
    for (int i = 0; i < 4; i++) {
        int gm = bm + ty * 4 + i;
        if (gm >= M) continue;
        #pragma unroll
        for (int j = 0; j < 4; j++) {
            C[(size_t)gm * Nc + bn + tx * 4 + j] = c[i][j];
            if (Cbf) Cbf[(size_t)gm * Nc + bn + tx * 4 + j] = __float2bfloat16(c[i][j]);
        }
    }
}

// ---------------- layer 1 attention ----------------

__global__ void att1_kernel(const float* __restrict__ h1, const float* __restrict__ att_src,
                            const float* __restrict__ att_dst, float* __restrict__ a_s,
                            float* __restrict__ a_d) {
    int idx = blockIdx.x * blockDim.x + threadIdx.x;
    if (idx >= NN * H1) return;
    int n = idx >> 3, h = idx & 7;
    const float* row = h1 + (size_t)n * HID1 + h * D1;
    float s = 0.f, d = 0.f;
    #pragma unroll
    for (int k = 0; k < D1; k++) {
        float v = row[k];
        s += v * att_src[h * D1 + k];
        d += v * att_dst[h * D1 + k];
    }
    a_s[idx] = s;
    a_d[idx] = d;
}

__global__ void edge_e1_kernel(const int* __restrict__ eidx, const int* __restrict__ srcs,
                               const int* __restrict__ dst, const float* __restrict__ a_s,
                               const float* __restrict__ a_d, float* __restrict__ e1s) {
    int p = blockIdx.x * blockDim.x + threadIdx.x;
    if (p >= EE) return;
    int eid = eidx[p];
    int s = srcs[p];
    int d = dst[eid];
    #pragma unroll
    for (int h = 0; h < H1; h++) {
        float v = a_s[s * H1 + h] + a_d[d * H1 + h];
        e1s[(size_t)p * H1 + h] = (v >= 0.f) ? v : NEG_SLOPE * v;
    }
}

// wave per node: 8 heads x 8 lanes each
__global__ void softmax1_kernel(const int* __restrict__ row_ptr, const int* __restrict__ eidx,
                                float* __restrict__ e1s, float* __restrict__ alpha1_out) {
    int n = blockIdx.x * 4 + (threadIdx.x >> 6);
    int lane = threadIdx.x & 63;
    if (n >= NN) return;
    int start = row_ptr[n], end = row_ptr[n + 1];
    if (start == end) return;
    int h = lane & 7, j = lane >> 3;
    float m = -INFINITY;
    for (int p = start + j; p < end; p += 8) m = fmaxf(m, e1s[(size_t)p * 8 + h]);
    m = fmaxf(m, __shfl_xor(m, 8));
    m = fmaxf(m, __shfl_xor(m, 16));
    m = fmaxf(m, __shfl_xor(m, 32));
    float s = 0.f;
    for (int p = start + j; p < end; p += 8) s += expf(e1s[(size_t)p * 8 + h] - m);
    s += __shfl_xor(s, 8);
    s += __shfl_xor(s, 16);
    s += __shfl_xor(s, 32);
    float inv = 1.f / (s + 1e-16f);
    for (int p = start + j; p < end; p += 8) {
        float a = expf(e1s[(size_t)p * 8 + h] - m) * inv;
        e1s[(size_t)p * 8 + h] = a;
        alpha1_out[(size_t)eidx[p] * 8 + h] = a;
    }
}

// ---------------- layer 1 aggregation: wave-per-edge bf16 gathers ----------------
// block = 256 threads = 4 waves, one node per block.
// lane l covers dims [l*4, l*4+4) -> head h = l>>3. One dwordx2 (4 bf16) per lane per edge.

#define CH1 128
__global__ __launch_bounds__(256) void agg1_kernel(const int* __restrict__ row_ptr,
                                                   const int* __restrict__ srcs,
                                                   const float* __restrict__ e1s,   // alpha, [p][8]
                                                   const __hip_bfloat16* __restrict__ h1bf,
                                                   const float* __restrict__ b1,
                                                   float* __restrict__ x1) {
    __shared__ int s_src[CH1];
    __shared__ float s_al[CH1][8];
    __shared__ float red[4][HID1];
    int n = blockIdx.x;
    int tid = threadIdx.x;
    int w = tid >> 6, l = tid & 63;
    int h = l >> 3;
    int start = row_ptr[n], end = row_ptr[n + 1];
    float a0 = 0.f, a1 = 0.f, a2 = 0.f, a3 = 0.f;
    for (int c0 = start; c0 < end; c0 += CH1) {
        int cnt = min(CH1, end - c0);
        for (int i = tid; i < cnt; i += 256) s_src[i] = srcs[c0 + i];
        for (int i = tid; i < cnt * 8; i += 256) ((float*)s_al)[i] = e1s[(size_t)c0 * 8 + i];
        __syncthreads();
        int j = w;
        for (; j + 4 < cnt; j += 8) {
            int s0 = s_src[j], s1 = s_src[j + 4];
            float al0 = s_al[j][h], al1 = s_al[j + 4][h];
            const ushort4* r0 = (const ushort4*)(h1bf + (size_t)s0 * HID1);
            const ushort4* r1 = (const ushort4*)(h1bf + (size_t)s1 * HID1);
            ushort4 v0 = r0[l];
            ushort4 v1 = r1[l];
            a0 += al0 * bf2f(v0.x); a1 += al0 * bf2f(v0.y);
            a2 += al0 * bf2f(v0.z); a3 += al0 * bf2f(v0.w);
            a0 += al1 * bf2f(v1.x); a1 += al1 * bf2f(v1.y);
            a2 += al1 * bf2f(v1.z); a3 += al1 * bf2f(v1.w);
        }
        if (j < cnt) {
            int s0 = s_src[j];
            float al0 = s_al[j][h];
            const ushort4* r0 = (const ushort4*)(h1bf + (size_t)s0 * HID1);
            ushort4 v0 = r0[l];
            a0 += al0 * bf2f(v0.x); a1 += al0 * bf2f(v0.y);
            a2 += al0 * bf2f(v0.z); a3 += al0 * bf2f(v0.w);
        }
        __syncthreads();
    }
    red[w][l * 4 + 0] = a0;
    red[w][l * 4 + 1] = a1;
    red[w][l * 4 + 2] = a2;
    red[w][l * 4 + 3] = a3;
    __syncthreads();
    float r = red[0][tid] + red[1][tid] + red[2][tid] + red[3][tid] + b1[tid];
    x1[(size_t)n * HID1 + tid] = (r > 0.f) ? r : expf(r) - 1.f;  // ELU
}

// ---------------- layer 2 attention (1 head) ----------------

__global__ __launch_bounds__(64) void att2_kernel(const float* __restrict__ h2,
                                                  const float* __restrict__ att_src,
                                                  const float* __restrict__ att_dst,
                                                  float* __restrict__ a_s, float* __restrict__ a_d) {
    int n = blockIdx.x;
    int lane = threadIdx.x;
    const float* row = h2 + (size_t)n * HID2;
    float s = 0.f, d = 0.f;
    for (int k = lane; k < HID2; k += 64) {
        float v = row[k];
        s += v * att_src[k];
        d += v * att_dst[k];
    }
    for (int off = 32; off; off >>= 1) {
        s += __shfl_down(s, off);
        d += __shfl_down(d, off);
    }
    if (lane == 0) {
        a_s[n] = s;
        a_d[n] = d;
    }
}

__global__ void edge_e2_kernel(const int* __restrict__ eidx, const int* __restrict__ srcs,
                               const int* __restrict__ dst, const float* __restrict__ a_s,
                               const float* __restrict__ a_d, float* __restrict__ e2s) {
    int p = blockIdx.x * blockDim.x + threadIdx.x;
    if (p >= EE) return;
    int eid = eidx[p];
    float v = a_s[srcs[p]] + a_d[dst[eid]];
    e2s[p] = (v >= 0.f) ? v : NEG_SLOPE * v;
}

__global__ void softmax2_kernel(const int* __restrict__ row_ptr, const int* __restrict__ eidx,
                                float* __restrict__ e2s, float* __restrict__ alpha2_out) {
    int n = blockIdx.x * 4 + (threadIdx.x >> 6);
    int lane = threadIdx.x & 63;
    if (n >= NN) return;
    int start = row_ptr[n], end = row_ptr[n + 1];
    if (start == end) return;
    float m = -INFINITY;
    for (int p = start + lane; p < end; p += 64) m = fmaxf(m, e2s[p]);
    for (int off = 32; off; off >>= 1) m = fmaxf(m, __shfl_xor(m, off));
    float s = 0.f;
    for (int p = start + lane; p < end; p += 64) s += expf(e2s[p] - m);
    for (int off = 32; off; off >>= 1) s += __shfl_xor(s, off);
    float inv = 1.f / (s + 1e-16f);
    for (int p = start + lane; p < end; p += 64) {
        float a = expf(e2s[p] - m) * inv;
        e2s[p] = a;
        alpha2_out[eidx[p]] = a;
    }
}

// ---------------- layer 2 aggregation: wave-per-edge bf16 gathers ----------------
// lane l covers dims [l*2, l*2+2). One dword (2 bf16) per lane per edge.

#define CH2 256
__global__ __launch_bounds__(256) void agg2_kernel(const int* __restrict__ row_ptr,
                                                   const int* __restrict__ srcs,
                                                   const float* __restrict__ e2s,  // alpha [p]
                                                   const __hip_bfloat16* __restrict__ h2bf,
                                                   const float* __restrict__ b2,
                                                   float* __restrict__ x2) {
    __shared__ int s_src[CH2];
    __shared__ float s_al[CH2];
    __shared__ float red[4][HID2];
    int n = blockIdx.x;
    int tid = threadIdx.x;
    int w = tid >> 6, l = tid & 63;
    int start = row_ptr[n], end = row_ptr[n + 1];
    float a0 = 0.f, a1 = 0.f;
    for (int c0 = start; c0 < end; c0 += CH2) {
        int cnt = min(CH2, end - c0);
        for (int i = tid; i < cnt; i += 256) {
            s_src[i] = srcs[c0 + i];
            s_al[i] = e2s[c0 + i];
        }
        __syncthreads();
        int j = w;
        for (; j + 4 < cnt; j += 8) {
            int s0 = s_src[j], s1 = s_src[j + 4];
            float al0 = s_al[j], al1 = s_al[j + 4];
            const unsigned int* r0 = (const unsigned int*)(h2bf + (size_t)s0 * HID2);
            const unsigned int* r1 = (const unsigned int*)(h2bf + (size_t)s1 * HID2);
            unsigned int v0 = r0[l];
            unsigned int v1 = r1[l];
            a0 += al0 * bf2f((unsigned short)(v0 & 0xffff));
            a1 += al0 * bf2f((unsigned short)(v0 >> 16));
            a0 += al1 * bf2f((unsigned short)(v1 & 0xffff));
            a1 += al1 * bf2f((unsigned short)(v1 >> 16));
        }
        if (j < cnt) {
            int s0 = s_src[j];
            float al0 = s_al[j];
            const unsigned int* r0 = (const unsigned int*)(h2bf + (size_t)s0 * HID2);
            unsigned int v0 = r0[l];
            a0 += al0 * bf2f((unsigned short)(v0 & 0xffff));
            a1 += al0 * bf2f((unsigned short)(v0 >> 16));
        }
        __syncthreads();
    }
    red[w][l * 2 + 0] = a0;
    red[w][l * 2 + 1] = a1;
    __syncthreads();
    if (tid < HID2) {
        float r = red[0][tid] + red[1][tid] + red[2][tid] + red[3][tid] + b2[tid];
        x2[(size_t)n * HID2 + tid] = (r > 0.f) ? r : 0.f;  // ReLU
    }
}

// ---------------- fused FC head: 8 nodes per block of 512 threads ----------------

#define NT 8
__global__ __launch_bounds__(512) void fc_kernel(const float* __restrict__ x2,
                                                 const float* __restrict__ fcW1,
                                                 const float* __restrict__ fcb1,
                                                 const float* __restrict__ fcW2,
                                                 const float* __restrict__ fcb2,
                                                 float* __restrict__ out) {
    __shared__ float xs[NT][HID2];
    __shared__ float red[NT][8];
    int n0 = blockIdx.x * NT;
    int tid = threadIdx.x;
    for (int i = tid; i < NT * HID2; i += 512) {
        int ni = i >> 7;
        int d = i & 127;
        int gn = n0 + ni;
        xs[ni][d] = (gn < NN) ? x2[(size_t)gn * HID2 + d] : 0.f;
    }
    __syncthreads();
    int k = tid;  // 0..511
    float hv[NT] = {};
    for (int d = 0; d < HID2; d++) {
        float w = fcW1[d * FC1 + k];
        #pragma unroll
        for (int i = 0; i < NT; i++) hv[i] += xs[i][d] * w;
    }
    float b = fcb1[k], w2 = fcW2[k];
    #pragma unroll
    for (int i = 0; i < NT; i++) {
        float hh = hv[i] + b;
        hv[i] = ((hh > 0.f) ? hh : 0.f) * w2;
    }
    int wave = tid >> 6, lane = tid & 63;
    #pragma unroll
    for (int i = 0; i < NT; i++) {
        float v = hv[i];
        for (int off = 32; off; off >>= 1) v += __shfl_down(v, off);
        if (lane == 0) red[i][wave] = v;
    }
    __syncthreads();
    if (tid < NT) {
        float s = fcb2[0];
        #pragma unroll
        for (int w = 0; w < 8; w++) s += red[tid][w];
        int gn = n0 + tid;
        if (gn < NN) out[gn] = s;
    }
}

// ---------------- host launch ----------------

extern "C" void kernel_launch(void* const* d_in, const int* in_sizes, int n_in,
                              void* d_out, int out_size, void* d_ws, size_t ws_size,
                              hipStream_t stream) {
    (void)in_sizes; (void)n_in; (void)out_size; (void)ws_size;
    const float* x        = (const float*)d_in[0];
    const int*   eindex   = (const int*)d_in[1];
    const float* W1       = (const float*)d_in[2];
    const float* att_src1 = (const float*)d_in[3];
    const float* att_dst1 = (const float*)d_in[4];
    const float* b1       = (const float*)d_in[5];
    const float* W2       = (const float*)d_in[6];
    const float* att_src2 = (const float*)d_in[7];
    const float* att_dst2 = (const float*)d_in[8];
    const float* b2       = (const float*)d_in[9];
    const float* fcW1     = (const float*)d_in[10];
    const float* fcb1     = (const float*)d_in[11];
    const float* fcW2     = (const float*)d_in[12];
    const float* fcb2     = (const float*)d_in[13];

    const int* src = eindex;
    const int* dst = eindex + EE;

    float* out_n      = (float*)d_out;               // [N]
    float* alpha1_out = out_n + NN;                  // [E,8]
    float* alpha2_out = alpha1_out + (size_t)EE * 8; // [E]

    // workspace layout (aligned 256B)
    char* ws = (char*)d_ws;
    size_t off = 0;
    auto alloc = [&](size_t bytes) {
        size_t o = off;
        off = (off + bytes + 255) & ~(size_t)255;
        return o;
    };
    size_t o_rowptr = alloc((NN + 1) * sizeof(int));
    size_t o_cursor = alloc(NN * sizeof(int));
    size_t o_eidx   = alloc(EE * sizeof(int));
    size_t o_srcs   = alloc(EE * sizeof(int));
    size_t o_h1     = alloc((size_t)NN * HID1 * sizeof(float)); // reused: h2 (first half), x2 (second half)
    size_t o_x1     = alloc((size_t)NN * HID1 * sizeof(float));
    size_t o_e1s    = alloc((size_t)EE * H1 * sizeof(float));   // reused: e2s
    size_t o_as1    = alloc((size_t)NN * H1 * sizeof(float));   // reused: a_s2
    size_t o_ad1    = alloc((size_t)NN * H1 * sizeof(float));   // reused: a_d2
    size_t o_h1bf   = alloc((size_t)NN * HID1 * sizeof(__hip_bfloat16));
    size_t o_h2bf   = alloc((size_t)NN * HID2 * sizeof(__hip_bfloat16));

    int*   row_ptr = (int*)(ws + o_rowptr);
    int*   cursor  = (int*)(ws + o_cursor);
    int*   eidx    = (int*)(ws + o_eidx);
    int*   srcs    = (int*)(ws + o_srcs);
    float* h1      = (float*)(ws + o_h1);
    float* x1      = (float*)(ws + o_x1);
    float* e1s     = (float*)(ws + o_e1s);
    float* a_s1    = (float*)(ws + o_as1);
    float* a_d1    = (float*)(ws + o_ad1);
    __hip_bfloat16* h1bf = (__hip_bfloat16*)(ws + o_h1bf);
    __hip_bfloat16* h2bf = (__hip_bfloat16*)(ws + o_h2bf);
    // aliases for layer 2
    float* h2   = h1;                                   // [N,128]
    float* x2   = h1 + (size_t)NN * HID2;               // [N,128]
    float* e2s  = e1s;                                  // [E]
    float* a_s2 = a_s1;                                 // [N]
    float* a_d2 = a_d1;                                 // [N]

    // ---- build CSR by dst ----
    fill_zero_int<<<(NN + 255) / 256, 256, 0, stream>>>(cursor, NN);
    hist_kernel<<<(EE + 255) / 256, 256, 0, stream>>>(dst, cursor);
    scan_kernel<<<1, 1024, 0, stream>>>(cursor, row_ptr, NN);
    scatter_kernel<<<(EE + 255) / 256, 256, 0, stream>>>(src, dst, cursor, eidx, srcs);

    // ---- layer 1 ----
    gemm_kernel<<<dim3((NN + 63) / 64, HID1 / 64), 256, 0, stream>>>(x, W1, h1, h1bf, NN, IN_DIM, HID1);
    att1_kernel<<<(NN * H1 + 255) / 256, 256, 0, stream>>>(h1, att_src1, att_dst1, a_s1, a_d1);
    edge_e1_kernel<<<(EE + 255) / 256, 256, 0, stream>>>(eidx, srcs, dst, a_s1, a_d1, e1s);
    softmax1_kernel<<<(NN + 3) / 4, 256, 0, stream>>>(row_ptr, eidx, e1s, alpha1_out);
    agg1_kernel<<<NN, 256, 0, stream>>>(row_ptr, srcs, e1s, h1bf, b1, x1);

    // ---- layer 2 ----
    gemm_kernel<<<dim3((NN + 63) / 64, HID2 / 64), 256, 0, stream>>>(x1, W2, h2, h2bf, NN, HID1, HID2);
    att2_kernel<<<NN, 64, 0, stream>>>(h2, att_src2, att_dst2, a_s2, a_d2);
    edge_e2_kernel<<<(EE + 255) / 256, 256, 0, stream>>>(eidx, srcs, dst, a_s2, a_d2, e2s);
    softmax2_kernel<<<(NN + 3) / 4, 256, 0, stream>>>(row_ptr, eidx, e2s, alpha2_out);
    agg2_kernel<<<NN, 256, 0, stream>>>(row_ptr, srcs, e2s, h2bf, b2, x2);

    // ---- FC head ----
    fc_kernel<<<(NN + NT - 1) / NT, 512, 0, stream>>>(x2, fcW1, fcb1, fcW2, fcb2, out_n);
}

// Round 3
// 512.809 us; speedup vs baseline: 1.5640x; 1.3489x over previous
//
#include <hip/hip_runtime.h>
#include <hip/hip_bf16.h>
#include <math.h>

#define NN 50000
#define EE 800000
#define IN_DIM 128
#define H1 8
#define D1 32
#define HID1 256
#define HID2 128
#define FC1 512
#define NEG_SLOPE 0.2f

typedef short v8s __attribute__((ext_vector_type(8)));
typedef float v4f __attribute__((ext_vector_type(4)));

__device__ __forceinline__ float bf2f(unsigned short u) {
    unsigned int x = ((unsigned int)u) << 16;
    return __uint_as_float(x);
}
__device__ __forceinline__ short f2bf_s(float v) {
    __hip_bfloat16 h = __float2bfloat16(v);
    return *(short*)&h;
}

// ---------------- utility kernels ----------------

__global__ void fill_zero_int(int* p, int n) {
    int i = blockIdx.x * blockDim.x + threadIdx.x;
    if (i < n) p[i] = 0;
}

__global__ void hist_kernel(const int* __restrict__ dst, int* __restrict__ counts) {
    int e = blockIdx.x * blockDim.x + threadIdx.x;
    if (e < EE) atomicAdd(&counts[dst[e]], 1);
}

__global__ __launch_bounds__(1024) void scan_kernel(int* __restrict__ counts_cursor,
                                                    int* __restrict__ row_ptr, int n) {
    __shared__ int lds[1024];
    int tid = threadIdx.x;
    int carry = 0;
    int nchunks = (n + 1023) / 1024;
    for (int c = 0; c < nchunks; c++) {
        int idx = c * 1024 + tid;
        int v = (idx < n) ? counts_cursor[idx] : 0;
        lds[tid] = v;
        __syncthreads();
        for (int off = 1; off < 1024; off <<= 1) {
            int t = (tid >= off) ? lds[tid - off] : 0;
            __syncthreads();
            lds[tid] += t;
            __syncthreads();
        }
        int inc = lds[tid];
        int total = lds[1023];
        if (idx < n) {
            int ex = carry + inc - v;
            row_ptr[idx] = ex;
            counts_cursor[idx] = ex;
        }
        carry += total;
        __syncthreads();
    }
    if (tid == 0) row_ptr[n] = carry;
}

__global__ void scatter_kernel(const int* __restrict__ src, const int* __restrict__ dst,
                               int* __restrict__ cursor, int* __restrict__ eidx,
                               int* __restrict__ srcs) {
    int e = blockIdx.x * blockDim.x + threadIdx.x;
    if (e >= EE) return;
    int d = dst[e];
    int p = atomicAdd(&cursor[d], 1);
    eidx[p] = e;
    srcs[p] = src[e];
}

// float -> bf16 elementwise
__global__ void cvt_bf16_kernel(const float* __restrict__ in, __hip_bfloat16* __restrict__ out, int n) {
    int i = blockIdx.x * blockDim.x + threadIdx.x;
    if (i < n) out[i] = __float2bfloat16(in[i]);
}

// pack fp32 weight B[K][N] into MFMA fragment-major bf16: Bp[((ntile*KS+ks)*64+lane)*8+j]
// lane = (n&15) | ((kk>>3)<<4), j = kk&7, kk = k&31, ks = k>>5, ntile = n>>4
__global__ void pack_kernel(const float* __restrict__ B, __hip_bfloat16* __restrict__ Bp,
                            int K, int N) {
    int idx = blockIdx.x * blockDim.x + threadIdx.x;
    if (idx >= K * N) return;
    int k = idx / N, n = idx % N;
    int ntile = n >> 4, ks = k >> 5, kk = k & 31;
    int lane = (n & 15) | ((kk >> 3) << 4);
    int j = kk & 7;
    int KS = K >> 5;
    Bp[((size_t)(ntile * KS + ks) * 64 + lane) * 8 + j] = __float2bfloat16(B[idx]);
}

// ---------------- MFMA GEMM: C[M,N] = A[M,K] @ B[K,N], bf16 in / fp32 out (+bf16 copy) ----
// block: 4 waves; wave w covers rows [bm + w*32, +32), cols [bn, bn+64).
// A row-major bf16, B packed fragment-major.

__global__ __launch_bounds__(256) void mgemm_kernel(const __hip_bfloat16* __restrict__ A,
                                                    const __hip_bfloat16* __restrict__ Bp,
                                                    float* __restrict__ C,
                                                    __hip_bfloat16* __restrict__ Cbf,
                                                    int M, int K, int N) {
    int w = threadIdx.x >> 6, l = threadIdx.x & 63;
    int bm = blockIdx.x * 128 + w * 32;
    int bn = blockIdx.y * 64;
    int lr = l & 15, lk = l >> 4;
    int KS = K >> 5;
    const short* Ab = (const short*)A;
    const short* Bb = (const short*)Bp;
    v4f acc[2][4];
    #pragma unroll
    for (int mi = 0; mi < 2; mi++)
        #pragma unroll
        for (int nt = 0; nt < 4; nt++) acc[mi][nt] = (v4f)(0.f);
    for (int ks = 0; ks < KS; ks++) {
        v8s a[2];
        #pragma unroll
        for (int mi = 0; mi < 2; mi++) {
            int gm = bm + mi * 16 + lr;
            a[mi] = (gm < M) ? *(const v8s*)(Ab + (size_t)gm * K + ks * 32 + lk * 8)
                             : (v8s)(short)0;
        }
        #pragma unroll
        for (int nt = 0; nt < 4; nt++) {
            int ntile = (bn >> 4) + nt;
            v8s b = *(const v8s*)(Bb + ((size_t)(ntile * KS + ks) * 64 + l) * 8);
            acc[0][nt] = __builtin_amdgcn_mfma_f32_16x16x32_bf16(a[0], b, acc[0][nt], 0, 0, 0);
            acc[1][nt] = __builtin_amdgcn_mfma_f32_16x16x32_bf16(a[1], b, acc[1][nt], 0, 0, 0);
        }
    }
    #pragma unroll
    for (int mi = 0; mi < 2; mi++) {
        #pragma unroll
        for (int nt = 0; nt < 4; nt++) {
            int gn = bn + nt * 16 + lr;
            #pragma unroll
            for (int j = 0; j < 4; j++) {
                int gm = bm + mi * 16 + lk * 4 + j;
                if (gm < M) {
                    float v = acc[mi][nt][j];
                    C[(size_t)gm * N + gn] = v;
                    Cbf[(size_t)gm * N + gn] = __float2bfloat16(v);
                }
            }
        }
    }
}

// ---------------- fused FC head via MFMA ----------------
// block: 4 waves; all waves share rows [bm, bm+32); wave w covers cols [w*128, +128).
// h = relu(x2 @ fcW1 + fcb1); out = h @ fcW2 + fcb2, reduced in-register + LDS.

__global__ __launch_bounds__(256) void fc_mfma_kernel(const __hip_bfloat16* __restrict__ A,
                                                      const __hip_bfloat16* __restrict__ Bp,
                                                      const float* __restrict__ fcb1,
                                                      const float* __restrict__ fcW2,
                                                      const float* __restrict__ fcb2,
                                                      float* __restrict__ out) {
    __shared__ float red[4][32];
    int w = threadIdx.x >> 6, l = threadIdx.x & 63;
    int bm = blockIdx.x * 32;
    int lr = l & 15, lk = l >> 4;
    const int K = HID2, KS = K >> 5;  // 4
    const short* Ab = (const short*)A;
    const short* Bb = (const short*)Bp;
    v4f acc[2][8];
    #pragma unroll
    for (int mi = 0; mi < 2; mi++)
        #pragma unroll
        for (int nt = 0; nt < 8; nt++) acc[mi][nt] = (v4f)(0.f);
    for (int ks = 0; ks < KS; ks++) {
        v8s a[2];
        #pragma unroll
        for (int mi = 0; mi < 2; mi++) {
            int gm = bm + mi * 16 + lr;
            a[mi] = (gm < NN) ? *(const v8s*)(Ab + (size_t)gm * K + ks * 32 + lk * 8)
                              : (v8s)(short)0;
        }
        #pragma unroll
        for (int nt = 0; nt < 8; nt++) {
            int ntile = w * 8 + nt;
            v8s b = *(const v8s*)(Bb + ((size_t)(ntile * KS + ks) * 64 + l) * 8);
            acc[0][nt] = __builtin_amdgcn_mfma_f32_16x16x32_bf16(a[0], b, acc[0][nt], 0, 0, 0);
            acc[1][nt] = __builtin_amdgcn_mfma_f32_16x16x32_bf16(a[1], b, acc[1][nt], 0, 0, 0);
        }
    }
    // epilogue: relu(+fcb1)*fcW2, sum over this wave's 128 cols
    float p[2][4];
    #pragma unroll
    for (int mi = 0; mi < 2; mi++)
        #pragma unroll
        for (int j = 0; j < 4; j++) p[mi][j] = 0.f;
    #pragma unroll
    for (int nt = 0; nt < 8; nt++) {
        int col = w * 128 + nt * 16 + lr;
        float b1v = fcb1[col], w2v = fcW2[col];
        #pragma unroll
        for (int mi = 0; mi < 2; mi++) {
            #pragma unroll
            for (int j = 0; j < 4; j++) {
                float v = acc[mi][nt][j] + b1v;
                p[mi][j] += ((v > 0.f) ? v : 0.f) * w2v;
            }
        }
    }
    // reduce over the 16 lanes (lr) that hold different cols of the same row
    #pragma unroll
    for (int mi = 0; mi < 2; mi++)
        #pragma unroll
        for (int j = 0; j < 4; j++) {
            float v = p[mi][j];
            v += __shfl_xor(v, 1);
            v += __shfl_xor(v, 2);
            v += __shfl_xor(v, 4);
            v += __shfl_xor(v, 8);
            p[mi][j] = v;
        }
    if (lr == 0) {
        #pragma unroll
        for (int mi = 0; mi < 2; mi++)
            #pragma unroll
            for (int j = 0; j < 4; j++) red[w][mi * 16 + lk * 4 + j] = p[mi][j];
    }
    __syncthreads();
    int tid = threadIdx.x;
    if (tid < 32) {
        int gm = bm + tid;
        if (gm < NN)
            out[gm] = red[0][tid] + red[1][tid] + red[2][tid] + red[3][tid] + fcb2[0];
    }
}

// ---------------- layer 1 attention ----------------

__global__ void att1_kernel(const float* __restrict__ h1, const float* __restrict__ att_src,
                            const float* __restrict__ att_dst, float* __restrict__ a_s,
                            float* __restrict__ a_d) {
    int idx = blockIdx.x * blockDim.x + threadIdx.x;
    if (idx >= NN * H1) return;
    int n = idx >> 3, h = idx & 7;
    const float* row = h1 + (size_t)n * HID1 + h * D1;
    float s = 0.f, d = 0.f;
    #pragma unroll
    for (int k = 0; k < D1; k++) {
        float v = row[k];
        s += v * att_src[h * D1 + k];
        d += v * att_dst[h * D1 + k];
    }
    a_s[idx] = s;
    a_d[idx] = d;
}

__global__ void edge_e1_kernel(const int* __restrict__ eidx, const int* __restrict__ srcs,
                               const int* __restrict__ dst, const float* __restrict__ a_s,
                               const float* __restrict__ a_d, float* __restrict__ e1s) {
    int p = blockIdx.x * blockDim.x + threadIdx.x;
    if (p >= EE) return;
    int eid = eidx[p];
    int s = srcs[p];
    int d = dst[eid];
    #pragma unroll
    for (int h = 0; h < H1; h++) {
        float v = a_s[s * H1 + h] + a_d[d * H1 + h];
        e1s[(size_t)p * H1 + h] = (v >= 0.f) ? v : NEG_SLOPE * v;
    }
}

__global__ void softmax1_kernel(const int* __restrict__ row_ptr, const int* __restrict__ eidx,
                                float* __restrict__ e1s, float* __restrict__ alpha1_out) {
    int n = blockIdx.x * 4 + (threadIdx.x >> 6);
    int lane = threadIdx.x & 63;
    if (n >= NN) return;
    int start = row_ptr[n], end = row_ptr[n + 1];
    if (start == end) return;
    int h = lane & 7, j = lane >> 3;
    float m = -INFINITY;
    for (int p = start + j; p < end; p += 8) m = fmaxf(m, e1s[(size_t)p * 8 + h]);
    m = fmaxf(m, __shfl_xor(m, 8));
    m = fmaxf(m, __shfl_xor(m, 16));
    m = fmaxf(m, __shfl_xor(m, 32));
    float s = 0.f;
    for (int p = start + j; p < end; p += 8) s += expf(e1s[(size_t)p * 8 + h] - m);
    s += __shfl_xor(s, 8);
    s += __shfl_xor(s, 16);
    s += __shfl_xor(s, 32);
    float inv = 1.f / (s + 1e-16f);
    for (int p = start + j; p < end; p += 8) {
        float a = expf(e1s[(size_t)p * 8 + h] - m) * inv;
        e1s[(size_t)p * 8 + h] = a;
        alpha1_out[(size_t)eidx[p] * 8 + h] = a;
    }
}

// ---------------- layer 1 aggregation (bf16 gathers, writes bf16 x1) ----------------

#define CH1 128
__global__ __launch_bounds__(256) void agg1_kernel(const int* __restrict__ row_ptr,
                                                   const int* __restrict__ srcs,
                                                   const float* __restrict__ e1s,
                                                   const __hip_bfloat16* __restrict__ h1bf,
                                                   const float* __restrict__ b1,
                                                   __hip_bfloat16* __restrict__ x1bf) {
    __shared__ int s_src[CH1];
    __shared__ float s_al[CH1][8];
    __shared__ float red[4][HID1];
    int n = blockIdx.x;
    int tid = threadIdx.x;
    int w = tid >> 6, l = tid & 63;
    int h = l >> 3;
    int start = row_ptr[n], end = row_ptr[n + 1];
    float a0 = 0.f, a1 = 0.f, a2 = 0.f, a3 = 0.f;
    for (int c0 = start; c0 < end; c0 += CH1) {
        int cnt = min(CH1, end - c0);
        for (int i = tid; i < cnt; i += 256) s_src[i] = srcs[c0 + i];
        for (int i = tid; i < cnt * 8; i += 256) ((float*)s_al)[i] = e1s[(size_t)c0 * 8 + i];
        __syncthreads();
        int j = w;
        for (; j + 4 < cnt; j += 8) {
            int s0 = s_src[j], s1 = s_src[j + 4];
            float al0 = s_al[j][h], al1 = s_al[j + 4][h];
            const ushort4* r0 = (const ushort4*)(h1bf + (size_t)s0 * HID1);
            const ushort4* r1 = (const ushort4*)(h1bf + (size_t)s1 * HID1);
            ushort4 v0 = r0[l];
            ushort4 v1 = r1[l];
            a0 += al0 * bf2f(v0.x); a1 += al0 * bf2f(v0.y);
            a2 += al0 * bf2f(v0.z); a3 += al0 * bf2f(v0.w);
            a0 += al1 * bf2f(v1.x); a1 += al1 * bf2f(v1.y);
            a2 += al1 * bf2f(v1.z); a3 += al1 * bf2f(v1.w);
        }
        if (j < cnt) {
            int s0 = s_src[j];
            float al0 = s_al[j][h];
            const ushort4* r0 = (const ushort4*)(h1bf + (size_t)s0 * HID1);
            ushort4 v0 = r0[l];
            a0 += al0 * bf2f(v0.x); a1 += al0 * bf2f(v0.y);
            a2 += al0 * bf2f(v0.z); a3 += al0 * bf2f(v0.w);
        }
        __syncthreads();
    }
    red[w][l * 4 + 0] = a0;
    red[w][l * 4 + 1] = a1;
    red[w][l * 4 + 2] = a2;
    red[w][l * 4 + 3] = a3;
    __syncthreads();
    float r = red[0][tid] + red[1][tid] + red[2][tid] + red[3][tid] + b1[tid];
    r = (r > 0.f) ? r : expf(r) - 1.f;  // ELU
    x1bf[(size_t)n * HID1 + tid] = __float2bfloat16(r);
}

// ---------------- layer 2 attention (1 head) ----------------

__global__ __launch_bounds__(64) void att2_kernel(const float* __restrict__ h2,
                                                  const float* __restrict__ att_src,
                                                  const float* __restrict__ att_dst,
                                                  float* __restrict__ a_s, float* __restrict__ a_d) {
    int n = blockIdx.x;
    int lane = threadIdx.x;
    const float* row = h2 + (size_t)n * HID2;
    float s = 0.f, d = 0.f;
    for (int k = lane; k < HID2; k += 64) {
        float v = row[k];
        s += v * att_src[k];
        d += v * att_dst[k];
    }
    for (int off = 32; off; off >>= 1) {
        s += __shfl_down(s, off);
        d += __shfl_down(d, off);
    }
    if (lane == 0) {
        a_s[n] = s;
        a_d[n] = d;
    }
}

__global__ void edge_e2_kernel(const int* __restrict__ eidx, const int* __restrict__ srcs,
                               const int* __restrict__ dst, const float* __restrict__ a_s,
                               const float* __restrict__ a_d, float* __restrict__ e2s) {
    int p = blockIdx.x * blockDim.x + threadIdx.x;
    if (p >= EE) return;
    int eid = eidx[p];
    float v = a_s[srcs[p]] + a_d[dst[eid]];
    e2s[p] = (v >= 0.f) ? v : NEG_SLOPE * v;
}

__global__ void softmax2_kernel(const int* __restrict__ row_ptr, const int* __restrict__ eidx,
                                float* __restrict__ e2s, float* __restrict__ alpha2_out) {
    int n = blockIdx.x * 4 + (threadIdx.x >> 6);
    int lane = threadIdx.x & 63;
    if (n >= NN) return;
    int start = row_ptr[n], end = row_ptr[n + 1];
    if (start == end) return;
    float m = -INFINITY;
    for (int p = start + lane; p < end; p += 64) m = fmaxf(m, e2s[p]);
    for (int off = 32; off; off >>= 1) m = fmaxf(m, __shfl_xor(m, off));
    float s = 0.f;
    for (int p = start + lane; p < end; p += 64) s += expf(e2s[p] - m);
    for (int off = 32; off; off >>= 1) s += __shfl_xor(s, off);
    float inv = 1.f / (s + 1e-16f);
    for (int p = start + lane; p < end; p += 64) {
        float a = expf(e2s[p] - m) * inv;
        e2s[p] = a;
        alpha2_out[eidx[p]] = a;
    }
}

// ---------------- layer 2 aggregation (bf16 gathers, writes bf16 x2) ----------------

#define CH2 256
__global__ __launch_bounds__(256) void agg2_kernel(const int* __restrict__ row_ptr,
                                                   const int* __restrict__ srcs,
                                                   const float* __restrict__ e2s,
                                                   const __hip_bfloat16* __restrict__ h2bf,
                                                   const float* __restrict__ b2,
                                                   __hip_bfloat16* __restrict__ x2bf) {
    __shared__ int s_src[CH2];
    __shared__ float s_al[CH2];
    __shared__ float red[4][HID2];
    int n = blockIdx.x;
    int tid = threadIdx.x;
    int w = tid >> 6, l = tid & 63;
    int start = row_ptr[n], end = row_ptr[n + 1];
    float a0 = 0.f, a1 = 0.f;
    for (int c0 = start; c0 < end; c0 += CH2) {
        int cnt = min(CH2, end - c0);
        for (int i = tid; i < cnt; i += 256) {
            s_src[i] = srcs[c0 + i];
            s_al[i] = e2s[c0 + i];
        }
        __syncthreads();
        int j = w;
        for (; j + 4 < cnt; j += 8) {
            int s0 = s_src[j], s1 = s_src[j + 4];
            float al0 = s_al[j], al1 = s_al[j + 4];
            const unsigned int* r0 = (const unsigned int*)(h2bf + (size_t)s0 * HID2);
            const unsigned int* r1 = (const unsigned int*)(h2bf + (size_t)s1 * HID2);
            unsigned int v0 = r0[l];
            unsigned int v1 = r1[l];
            a0 += al0 * bf2f((unsigned short)(v0 & 0xffff));
            a1 += al0 * bf2f((unsigned short)(v0 >> 16));
            a0 += al1 * bf2f((unsigned short)(v1 & 0xffff));
            a1 += al1 * bf2f((unsigned short)(v1 >> 16));
        }
        if (j < cnt) {
            int s0 = s_src[j];
            float al0 = s_al[j];
            const unsigned int* r0 = (const unsigned int*)(h2bf + (size_t)s0 * HID2);
            unsigned int v0 = r0[l];
            a0 += al0 * bf2f((unsigned short)(v0 & 0xffff));
            a1 += al0 * bf2f((unsigned short)(v0 >> 16));
        }
        __syncthreads();
    }
    red[w][l * 2 + 0] = a0;
    red[w][l * 2 + 1] = a1;
    __syncthreads();
    if (tid < HID2) {
        float r = red[0][tid] + red[1][tid] + red[2][tid] + red[3][tid] + b2[tid];
        r = (r > 0.f) ? r : 0.f;  // ReLU
        x2bf[(size_t)n * HID2 + tid] = __float2bfloat16(r);
    }
}

// ---------------- host launch ----------------

extern "C" void kernel_launch(void* const* d_in, const int* in_sizes, int n_in,
                              void* d_out, int out_size, void* d_ws, size_t ws_size,
                              hipStream_t stream) {
    (void)in_sizes; (void)n_in; (void)out_size; (void)ws_size;
    const float* x        = (const float*)d_in[0];
    const int*   eindex   = (const int*)d_in[1];
    const float* W1       = (const float*)d_in[2];
    const float* att_src1 = (const float*)d_in[3];
    const float* att_dst1 = (const float*)d_in[4];
    const float* b1       = (const float*)d_in[5];
    const float* W2       = (const float*)d_in[6];
    const float* att_src2 = (const float*)d_in[7];
    const float* att_dst2 = (const float*)d_in[8];
    const float* b2       = (const float*)d_in[9];
    const float* fcW1     = (const float*)d_in[10];
    const float* fcb1     = (const float*)d_in[11];
    const float* fcW2     = (const float*)d_in[12];
    const float* fcb2     = (const float*)d_in[13];

    const int* src = eindex;
    const int* dst = eindex + EE;

    float* out_n      = (float*)d_out;               // [N]
    float* alpha1_out = out_n + NN;                  // [E,8]
    float* alpha2_out = alpha1_out + (size_t)EE * 8; // [E]

    char* ws = (char*)d_ws;
    size_t off = 0;
    auto alloc = [&](size_t bytes) {
        size_t o = off;
        off = (off + bytes + 255) & ~(size_t)255;
        return o;
    };
    size_t o_rowptr = alloc((NN + 1) * sizeof(int));
    size_t o_cursor = alloc(NN * sizeof(int));
    size_t o_eidx   = alloc(EE * sizeof(int));
    size_t o_srcs   = alloc(EE * sizeof(int));
    size_t o_h1     = alloc((size_t)NN * HID1 * sizeof(float));           // h1 fp32; reused as h2 fp32
    size_t o_e1s    = alloc((size_t)EE * H1 * sizeof(float));             // reused: e2s
    size_t o_as1    = alloc((size_t)NN * H1 * sizeof(float));             // reused: a_s2
    size_t o_ad1    = alloc((size_t)NN * H1 * sizeof(float));             // reused: a_d2
    size_t o_h1bf   = alloc((size_t)NN * HID1 * sizeof(__hip_bfloat16)); // reused: h2bf
    size_t o_xbf    = alloc((size_t)NN * IN_DIM * sizeof(__hip_bfloat16));
    size_t o_x1bf   = alloc((size_t)NN * HID1 * sizeof(__hip_bfloat16));
    size_t o_x2bf   = alloc((size_t)NN * HID2 * sizeof(__hip_bfloat16));
    size_t o_W1p    = alloc((size_t)IN_DIM * HID1 * sizeof(__hip_bfloat16));
    size_t o_W2p    = alloc((size_t)HID1 * HID2 * sizeof(__hip_bfloat16));
    size_t o_fW1p   = alloc((size_t)HID2 * FC1 * sizeof(__hip_bfloat16));

    int*   row_ptr = (int*)(ws + o_rowptr);
    int*   cursor  = (int*)(ws + o_cursor);
    int*   eidx    = (int*)(ws + o_eidx);
    int*   srcs    = (int*)(ws + o_srcs);
    float* h1      = (float*)(ws + o_h1);
    float* e1s     = (float*)(ws + o_e1s);
    float* a_s1    = (float*)(ws + o_as1);
    float* a_d1    = (float*)(ws + o_ad1);
    __hip_bfloat16* h1bf  = (__hip_bfloat16*)(ws + o_h1bf);
    __hip_bfloat16* xbf   = (__hip_bfloat16*)(ws + o_xbf);
    __hip_bfloat16* x1bf  = (__hip_bfloat16*)(ws + o_x1bf);
    __hip_bfloat16* x2bf  = (__hip_bfloat16*)(ws + o_x2bf);
    __hip_bfloat16* W1p   = (__hip_bfloat16*)(ws + o_W1p);
    __hip_bfloat16* W2p   = (__hip_bfloat16*)(ws + o_W2p);
    __hip_bfloat16* fW1p  = (__hip_bfloat16*)(ws + o_fW1p);
    // layer-2 aliases
    float* h2   = h1;
    float* e2s  = e1s;
    float* a_s2 = a_s1;
    float* a_d2 = a_d1;
    __hip_bfloat16* h2bf = h1bf;

    // ---- build CSR by dst ----
    fill_zero_int<<<(NN + 255) / 256, 256, 0, stream>>>(cursor, NN);
    hist_kernel<<<(EE + 255) / 256, 256, 0, stream>>>(dst, cursor);
    scan_kernel<<<1, 1024, 0, stream>>>(cursor, row_ptr, NN);
    scatter_kernel<<<(EE + 255) / 256, 256, 0, stream>>>(src, dst, cursor, eidx, srcs);

    // ---- input conversions / weight packing ----
    cvt_bf16_kernel<<<(NN * IN_DIM + 255) / 256, 256, 0, stream>>>(x, xbf, NN * IN_DIM);
    pack_kernel<<<(IN_DIM * HID1 + 255) / 256, 256, 0, stream>>>(W1, W1p, IN_DIM, HID1);
    pack_kernel<<<(HID1 * HID2 + 255) / 256, 256, 0, stream>>>(W2, W2p, HID1, HID2);
    pack_kernel<<<(HID2 * FC1 + 255) / 256, 256, 0, stream>>>(fcW1, fW1p, HID2, FC1);

    // ---- layer 1 ----
    mgemm_kernel<<<dim3((NN + 127) / 128, HID1 / 64), 256, 0, stream>>>(
        xbf, W1p, h1, h1bf, NN, IN_DIM, HID1);
    att1_kernel<<<(NN * H1 + 255) / 256, 256, 0, stream>>>(h1, att_src1, att_dst1, a_s1, a_d1);
    edge_e1_kernel<<<(EE + 255) / 256, 256, 0, stream>>>(eidx, srcs, dst, a_s1, a_d1, e1s);
    softmax1_kernel<<<(NN + 3) / 4, 256, 0, stream>>>(row_ptr, eidx, e1s, alpha1_out);
    agg1_kernel<<<NN, 256, 0, stream>>>(row_ptr, srcs, e1s, h1bf, b1, x1bf);

    // ---- layer 2 ----
    mgemm_kernel<<<dim3((NN + 127) / 128, HID2 / 64), 256, 0, stream>>>(
        x1bf, W2p, h2, h2bf, NN, HID1, HID2);
    att2_kernel<<<NN, 64, 0, stream>>>(h2, att_src2, att_dst2, a_s2, a_d2);
    edge_e2_kernel<<<(EE + 255) / 256, 256, 0, stream>>>(eidx, srcs, dst, a_s2, a_d2, e2s);
    softmax2_kernel<<<(NN + 3) / 4, 256, 0, stream>>>(row_ptr, eidx, e2s, alpha2_out);
    agg2_kernel<<<NN, 256, 0, stream>>>(row_ptr, srcs, e2s, h2bf, b2, x2bf);

    // ---- FC head ----
    fc_mfma_kernel<<<(NN + 31) / 32, 256, 0, stream>>>(x2bf, fW1p, fcb1, fcW2, fcb2, out_n);
}

// Round 4
// 433.339 us; speedup vs baseline: 1.8508x; 1.1834x over previous
//
#include <hip/hip_runtime.h>
#include <hip/hip_bf16.h>
#include <math.h>

#define NN 50000
#define EE 800000
#define IN_DIM 128
#define H1 8
#define D1 32
#define HID1 256
#define HID2 128
#define FC1 512
#define NEG_SLOPE 0.2f

typedef short v8s __attribute__((ext_vector_type(8)));
typedef float v4f __attribute__((ext_vector_type(4)));

__device__ __forceinline__ float bf2f(unsigned short u) {
    unsigned int x = ((unsigned int)u) << 16;
    return __uint_as_float(x);
}

// ---------------- utility kernels ----------------

__global__ void fill_zero_int(int* p, int n) {
    int i = blockIdx.x * blockDim.x + threadIdx.x;
    if (i < n) p[i] = 0;
}

__global__ void hist_kernel(const int* __restrict__ dst, int* __restrict__ counts) {
    int e = blockIdx.x * blockDim.x + threadIdx.x;
    if (e < EE) atomicAdd(&counts[dst[e]], 1);
}

// ---- hierarchical exclusive scan: 49 blocks x 1024 elems -> block sums -> add-back ----

__global__ __launch_bounds__(256) void scan_a_kernel(const int* __restrict__ counts,
                                                     int* __restrict__ excl,
                                                     int* __restrict__ bsum, int n) {
    __shared__ int wsum[4];
    int tid = threadIdx.x;
    int base = blockIdx.x * 1024 + tid * 4;
    int v0 = 0, v1 = 0, v2 = 0, v3 = 0;
    if (base + 3 < n) {
        int4 t = *(const int4*)(counts + base);
        v0 = t.x; v1 = t.y; v2 = t.z; v3 = t.w;
    } else {
        if (base + 0 < n) v0 = counts[base + 0];
        if (base + 1 < n) v1 = counts[base + 1];
        if (base + 2 < n) v2 = counts[base + 2];
        if (base + 3 < n) v3 = counts[base + 3];
    }
    int tot = v0 + v1 + v2 + v3;
    int lane = tid & 63;
    int w = tid >> 6;
    int x = tot;
    #pragma unroll
    for (int off = 1; off < 64; off <<= 1) {
        int y = __shfl_up(x, off);
        if (lane >= off) x += y;
    }
    if (lane == 63) wsum[w] = x;
    __syncthreads();
    int woff = 0;
    for (int i = 0; i < w; i++) woff += wsum[i];
    int et = woff + x - tot;  // exclusive prefix of this thread's group-of-4
    if (base + 0 < n) excl[base + 0] = et;
    if (base + 1 < n) excl[base + 1] = et + v0;
    if (base + 2 < n) excl[base + 2] = et + v0 + v1;
    if (base + 3 < n) excl[base + 3] = et + v0 + v1 + v2;
    if (tid == 255) bsum[blockIdx.x] = woff + x;  // block total
}

__global__ __launch_bounds__(64) void scan_b_kernel(int* __restrict__ bsum,
                                                    int* __restrict__ row_ptr, int nb, int n) {
    int lane = threadIdx.x;
    int v = (lane < nb) ? bsum[lane] : 0;
    int x = v;
    #pragma unroll
    for (int off = 1; off < 64; off <<= 1) {
        int y = __shfl_up(x, off);
        if (lane >= off) x += y;
    }
    if (lane < nb) bsum[lane] = x - v;  // exclusive
    if (lane == 63) row_ptr[n] = x;     // grand total
}

__global__ __launch_bounds__(256) void scan_c_kernel(const int* __restrict__ excl,
                                                     const int* __restrict__ bsum,
                                                     int* __restrict__ row_ptr,
                                                     int* __restrict__ cursor, int n) {
    int base = blockIdx.x * 1024 + threadIdx.x * 4;
    int off = bsum[blockIdx.x];
    #pragma unroll
    for (int j = 0; j < 4; j++) {
        int i = base + j;
        if (i < n) {
            int r = excl[i] + off;
            row_ptr[i] = r;
            cursor[i] = r;
        }
    }
}

__global__ void scatter_kernel(const int* __restrict__ src, const int* __restrict__ dst,
                               int* __restrict__ cursor, int* __restrict__ eidx,
                               int* __restrict__ srcs) {
    int e = blockIdx.x * blockDim.x + threadIdx.x;
    if (e >= EE) return;
    int d = dst[e];
    int p = atomicAdd(&cursor[d], 1);
    eidx[p] = e;
    srcs[p] = src[e];
}

// float -> bf16 elementwise
__global__ void cvt_bf16_kernel(const float* __restrict__ in, __hip_bfloat16* __restrict__ out, int n) {
    int i = blockIdx.x * blockDim.x + threadIdx.x;
    if (i < n) out[i] = __float2bfloat16(in[i]);
}

// pack fp32 weight B[K][N] into MFMA fragment-major bf16: Bp[((ntile*KS+ks)*64+lane)*8+j]
__global__ void pack_kernel(const float* __restrict__ B, __hip_bfloat16* __restrict__ Bp,
                            int K, int N) {
    int idx = blockIdx.x * blockDim.x + threadIdx.x;
    if (idx >= K * N) return;
    int k = idx / N, n = idx % N;
    int ntile = n >> 4, ks = k >> 5, kk = k & 31;
    int lane = (n & 15) | ((kk >> 3) << 4);
    int j = kk & 7;
    int KS = K >> 5;
    Bp[((size_t)(ntile * KS + ks) * 64 + lane) * 8 + j] = __float2bfloat16(B[idx]);
}

// ---------------- MFMA GEMM: C[M,N] = A[M,K] @ B[K,N], bf16 in / fp32 out (+bf16 copy) ----

__global__ __launch_bounds__(256) void mgemm_kernel(const __hip_bfloat16* __restrict__ A,
                                                    const __hip_bfloat16* __restrict__ Bp,
                                                    float* __restrict__ C,
                                                    __hip_bfloat16* __restrict__ Cbf,
                                                    int M, int K, int N) {
    int w = threadIdx.x >> 6, l = threadIdx.x & 63;
    int bm = blockIdx.x * 128 + w * 32;
    int bn = blockIdx.y * 64;
    int lr = l & 15, lk = l >> 4;
    int KS = K >> 5;
    const short* Ab = (const short*)A;
    const short* Bb = (const short*)Bp;
    v4f acc[2][4];
    #pragma unroll
    for (int mi = 0; mi < 2; mi++)
        #pragma unroll
        for (int nt = 0; nt < 4; nt++) acc[mi][nt] = (v4f)(0.f);
    for (int ks = 0; ks < KS; ks++) {
        v8s a[2];
        #pragma unroll
        for (int mi = 0; mi < 2; mi++) {
            int gm = bm + mi * 16 + lr;
            a[mi] = (gm < M) ? *(const v8s*)(Ab + (size_t)gm * K + ks * 32 + lk * 8)
                             : (v8s)(short)0;
        }
        #pragma unroll
        for (int nt = 0; nt < 4; nt++) {
            int ntile = (bn >> 4) + nt;
            v8s b = *(const v8s*)(Bb + ((size_t)(ntile * KS + ks) * 64 + l) * 8);
            acc[0][nt] = __builtin_amdgcn_mfma_f32_16x16x32_bf16(a[0], b, acc[0][nt], 0, 0, 0);
            acc[1][nt] = __builtin_amdgcn_mfma_f32_16x16x32_bf16(a[1], b, acc[1][nt], 0, 0, 0);
        }
    }
    #pragma unroll
    for (int mi = 0; mi < 2; mi++) {
        #pragma unroll
        for (int nt = 0; nt < 4; nt++) {
            int gn = bn + nt * 16 + lr;
            #pragma unroll
            for (int j = 0; j < 4; j++) {
                int gm = bm + mi * 16 + lk * 4 + j;
                if (gm < M) {
                    float v = acc[mi][nt][j];
                    C[(size_t)gm * N + gn] = v;
                    Cbf[(size_t)gm * N + gn] = __float2bfloat16(v);
                }
            }
        }
    }
}

// ---------------- fused FC head via MFMA ----------------

__global__ __launch_bounds__(256) void fc_mfma_kernel(const __hip_bfloat16* __restrict__ A,
                                                      const __hip_bfloat16* __restrict__ Bp,
                                                      const float* __restrict__ fcb1,
                                                      const float* __restrict__ fcW2,
                                                      const float* __restrict__ fcb2,
                                                      float* __restrict__ out) {
    __shared__ float red[4][32];
    int w = threadIdx.x >> 6, l = threadIdx.x & 63;
    int bm = blockIdx.x * 32;
    int lr = l & 15, lk = l >> 4;
    const int K = HID2, KS = K >> 5;  // 4
    const short* Ab = (const short*)A;
    const short* Bb = (const short*)Bp;
    v4f acc[2][8];
    #pragma unroll
    for (int mi = 0; mi < 2; mi++)
        #pragma unroll
        for (int nt = 0; nt < 8; nt++) acc[mi][nt] = (v4f)(0.f);
    for (int ks = 0; ks < KS; ks++) {
        v8s a[2];
        #pragma unroll
        for (int mi = 0; mi < 2; mi++) {
            int gm = bm + mi * 16 + lr;
            a[mi] = (gm < NN) ? *(const v8s*)(Ab + (size_t)gm * K + ks * 32 + lk * 8)
                              : (v8s)(short)0;
        }
        #pragma unroll
        for (int nt = 0; nt < 8; nt++) {
            int ntile = w * 8 + nt;
            v8s b = *(const v8s*)(Bb + ((size_t)(ntile * KS + ks) * 64 + l) * 8);
            acc[0][nt] = __builtin_amdgcn_mfma_f32_16x16x32_bf16(a[0], b, acc[0][nt], 0, 0, 0);
            acc[1][nt] = __builtin_amdgcn_mfma_f32_16x16x32_bf16(a[1], b, acc[1][nt], 0, 0, 0);
        }
    }
    float p[2][4];
    #pragma unroll
    for (int mi = 0; mi < 2; mi++)
        #pragma unroll
        for (int j = 0; j < 4; j++) p[mi][j] = 0.f;
    #pragma unroll
    for (int nt = 0; nt < 8; nt++) {
        int col = w * 128 + nt * 16 + lr;
        float b1v = fcb1[col], w2v = fcW2[col];
        #pragma unroll
        for (int mi = 0; mi < 2; mi++) {
            #pragma unroll
            for (int j = 0; j < 4; j++) {
                float v = acc[mi][nt][j] + b1v;
                p[mi][j] += ((v > 0.f) ? v : 0.f) * w2v;
            }
        }
    }
    #pragma unroll
    for (int mi = 0; mi < 2; mi++)
        #pragma unroll
        for (int j = 0; j < 4; j++) {
            float v = p[mi][j];
            v += __shfl_xor(v, 1);
            v += __shfl_xor(v, 2);
            v += __shfl_xor(v, 4);
            v += __shfl_xor(v, 8);
            p[mi][j] = v;
        }
    if (lr == 0) {
        #pragma unroll
        for (int mi = 0; mi < 2; mi++)
            #pragma unroll
            for (int j = 0; j < 4; j++) red[w][mi * 16 + lk * 4 + j] = p[mi][j];
    }
    __syncthreads();
    int tid = threadIdx.x;
    if (tid < 32) {
        int gm = bm + tid;
        if (gm < NN)
            out[gm] = red[0][tid] + red[1][tid] + red[2][tid] + red[3][tid] + fcb2[0];
    }
}

// ---------------- layer 1 attention ----------------

__global__ void att1_kernel(const float* __restrict__ h1, const float* __restrict__ att_src,
                            const float* __restrict__ att_dst, float* __restrict__ a_s,
                            float* __restrict__ a_d) {
    int idx = blockIdx.x * blockDim.x + threadIdx.x;
    if (idx >= NN * H1) return;
    int n = idx >> 3, h = idx & 7;
    const float* row = h1 + (size_t)n * HID1 + h * D1;
    float s = 0.f, d = 0.f;
    #pragma unroll
    for (int k = 0; k < D1; k++) {
        float v = row[k];
        s += v * att_src[h * D1 + k];
        d += v * att_dst[h * D1 + k];
    }
    a_s[idx] = s;
    a_d[idx] = d;
}

__global__ void edge_e1_kernel(const int* __restrict__ eidx, const int* __restrict__ srcs,
                               const int* __restrict__ dst, const float* __restrict__ a_s,
                               const float* __restrict__ a_d, float* __restrict__ e1s) {
    int p = blockIdx.x * blockDim.x + threadIdx.x;
    if (p >= EE) return;
    int eid = eidx[p];
    int s = srcs[p];
    int d = dst[eid];
    #pragma unroll
    for (int h = 0; h < H1; h++) {
        float v = a_s[s * H1 + h] + a_d[d * H1 + h];
        e1s[(size_t)p * H1 + h] = (v >= 0.f) ? v : NEG_SLOPE * v;
    }
}

__global__ void softmax1_kernel(const int* __restrict__ row_ptr, const int* __restrict__ eidx,
                                float* __restrict__ e1s, float* __restrict__ alpha1_out) {
    int n = blockIdx.x * 4 + (threadIdx.x >> 6);
    int lane = threadIdx.x & 63;
    if (n >= NN) return;
    int start = row_ptr[n], end = row_ptr[n + 1];
    if (start == end) return;
    int h = lane & 7, j = lane >> 3;
    float m = -INFINITY;
    for (int p = start + j; p < end; p += 8) m = fmaxf(m, e1s[(size_t)p * 8 + h]);
    m = fmaxf(m, __shfl_xor(m, 8));
    m = fmaxf(m, __shfl_xor(m, 16));
    m = fmaxf(m, __shfl_xor(m, 32));
    float s = 0.f;
    for (int p = start + j; p < end; p += 8) s += expf(e1s[(size_t)p * 8 + h] - m);
    s += __shfl_xor(s, 8);
    s += __shfl_xor(s, 16);
    s += __shfl_xor(s, 32);
    float inv = 1.f / (s + 1e-16f);
    for (int p = start + j; p < end; p += 8) {
        float a = expf(e1s[(size_t)p * 8 + h] - m) * inv;
        e1s[(size_t)p * 8 + h] = a;
        alpha1_out[(size_t)eidx[p] * 8 + h] = a;
    }
}

// ---------------- layer 1 aggregation (bf16 gathers, writes bf16 x1) ----------------

#define CH1 128
__global__ __launch_bounds__(256) void agg1_kernel(const int* __restrict__ row_ptr,
                                                   const int* __restrict__ srcs,
                                                   const float* __restrict__ e1s,
                                                   const __hip_bfloat16* __restrict__ h1bf,
                                                   const float* __restrict__ b1,
                                                   __hip_bfloat16* __restrict__ x1bf) {
    __shared__ int s_src[CH1];
    __shared__ float s_al[CH1][8];
    __shared__ float red[4][HID1];
    int n = blockIdx.x;
    int tid = threadIdx.x;
    int w = tid >> 6, l = tid & 63;
    int h = l >> 3;
    int start = row_ptr[n], end = row_ptr[n + 1];
    float a0 = 0.f, a1 = 0.f, a2 = 0.f, a3 = 0.f;
    for (int c0 = start; c0 < end; c0 += CH1) {
        int cnt = min(CH1, end - c0);
        for (int i = tid; i < cnt; i += 256) s_src[i] = srcs[c0 + i];
        for (int i = tid; i < cnt * 8; i += 256) ((float*)s_al)[i] = e1s[(size_t)c0 * 8 + i];
        __syncthreads();
        int j = w;
        for (; j + 4 < cnt; j += 8) {
            int s0 = s_src[j], s1 = s_src[j + 4];
            float al0 = s_al[j][h], al1 = s_al[j + 4][h];
            const ushort4* r0 = (const ushort4*)(h1bf + (size_t)s0 * HID1);
            const ushort4* r1 = (const ushort4*)(h1bf + (size_t)s1 * HID1);
            ushort4 v0 = r0[l];
            ushort4 v1 = r1[l];
            a0 += al0 * bf2f(v0.x); a1 += al0 * bf2f(v0.y);
            a2 += al0 * bf2f(v0.z); a3 += al0 * bf2f(v0.w);
            a0 += al1 * bf2f(v1.x); a1 += al1 * bf2f(v1.y);
            a2 += al1 * bf2f(v1.z); a3 += al1 * bf2f(v1.w);
        }
        if (j < cnt) {
            int s0 = s_src[j];
            float al0 = s_al[j][h];
            const ushort4* r0 = (const ushort4*)(h1bf + (size_t)s0 * HID1);
            ushort4 v0 = r0[l];
            a0 += al0 * bf2f(v0.x); a1 += al0 * bf2f(v0.y);
            a2 += al0 * bf2f(v0.z); a3 += al0 * bf2f(v0.w);
        }
        __syncthreads();
    }
    red[w][l * 4 + 0] = a0;
    red[w][l * 4 + 1] = a1;
    red[w][l * 4 + 2] = a2;
    red[w][l * 4 + 3] = a3;
    __syncthreads();
    float r = red[0][tid] + red[1][tid] + red[2][tid] + red[3][tid] + b1[tid];
    r = (r > 0.f) ? r : expf(r) - 1.f;  // ELU
    x1bf[(size_t)n * HID1 + tid] = __float2bfloat16(r);
}

// ---------------- layer 2 attention (1 head) ----------------

__global__ __launch_bounds__(64) void att2_kernel(const float* __restrict__ h2,
                                                  const float* __restrict__ att_src,
                                                  const float* __restrict__ att_dst,
                                                  float* __restrict__ a_s, float* __restrict__ a_d) {
    int n = blockIdx.x;
    int lane = threadIdx.x;
    const float* row = h2 + (size_t)n * HID2;
    float s = 0.f, d = 0.f;
    for (int k = lane; k < HID2; k += 64) {
        float v = row[k];
        s += v * att_src[k];
        d += v * att_dst[k];
    }
    for (int off = 32; off; off >>= 1) {
        s += __shfl_down(s, off);
        d += __shfl_down(d, off);
    }
    if (lane == 0) {
        a_s[n] = s;
        a_d[n] = d;
    }
}

__global__ void edge_e2_kernel(const int* __restrict__ eidx, const int* __restrict__ srcs,
                               const int* __restrict__ dst, const float* __restrict__ a_s,
                               const float* __restrict__ a_d, float* __restrict__ e2s) {
    int p = blockIdx.x * blockDim.x + threadIdx.x;
    if (p >= EE) return;
    int eid = eidx[p];
    float v = a_s[srcs[p]] + a_d[dst[eid]];
    e2s[p] = (v >= 0.f) ? v : NEG_SLOPE * v;
}

__global__ void softmax2_kernel(const int* __restrict__ row_ptr, const int* __restrict__ eidx,
                                float* __restrict__ e2s, float* __restrict__ alpha2_out) {
    int n = blockIdx.x * 4 + (threadIdx.x >> 6);
    int lane = threadIdx.x & 63;
    if (n >= NN) return;
    int start = row_ptr[n], end = row_ptr[n + 1];
    if (start == end) return;
    float m = -INFINITY;
    for (int p = start + lane; p < end; p += 64) m = fmaxf(m, e2s[p]);
    for (int off = 32; off; off >>= 1) m = fmaxf(m, __shfl_xor(m, off));
    float s = 0.f;
    for (int p = start + lane; p < end; p += 64) s += expf(e2s[p] - m);
    for (int off = 32; off; off >>= 1) s += __shfl_xor(s, off);
    float inv = 1.f / (s + 1e-16f);
    for (int p = start + lane; p < end; p += 64) {
        float a = expf(e2s[p] - m) * inv;
        e2s[p] = a;
        alpha2_out[eidx[p]] = a;
    }
}

// ---------------- layer 2 aggregation (bf16 gathers, writes bf16 x2) ----------------

#define CH2 256
__global__ __launch_bounds__(256) void agg2_kernel(const int* __restrict__ row_ptr,
                                                   const int* __restrict__ srcs,
                                                   const float* __restrict__ e2s,
                                                   const __hip_bfloat16* __restrict__ h2bf,
                                                   const float* __restrict__ b2,
                                                   __hip_bfloat16* __restrict__ x2bf) {
    __shared__ int s_src[CH2];
    __shared__ float s_al[CH2];
    __shared__ float red[4][HID2];
    int n = blockIdx.x;
    int tid = threadIdx.x;
    int w = tid >> 6, l = tid & 63;
    int start = row_ptr[n], end = row_ptr[n + 1];
    float a0 = 0.f, a1 = 0.f;
    for (int c0 = start; c0 < end; c0 += CH2) {
        int cnt = min(CH2, end - c0);
        for (int i = tid; i < cnt; i += 256) {
            s_src[i] = srcs[c0 + i];
            s_al[i] = e2s[c0 + i];
        }
        __syncthreads();
        int j = w;
        for (; j + 4 < cnt; j += 8) {
            int s0 = s_src[j], s1 = s_src[j + 4];
            float al0 = s_al[j], al1 = s_al[j + 4];
            const unsigned int* r0 = (const unsigned int*)(h2bf + (size_t)s0 * HID2);
            const unsigned int* r1 = (const unsigned int*)(h2bf + (size_t)s1 * HID2);
            unsigned int v0 = r0[l];
            unsigned int v1 = r1[l];
            a0 += al0 * bf2f((unsigned short)(v0 & 0xffff));
            a1 += al0 * bf2f((unsigned short)(v0 >> 16));
            a0 += al1 * bf2f((unsigned short)(v1 & 0xffff));
            a1 += al1 * bf2f((unsigned short)(v1 >> 16));
        }
        if (j < cnt) {
            int s0 = s_src[j];
            float al0 = s_al[j];
            const unsigned int* r0 = (const unsigned int*)(h2bf + (size_t)s0 * HID2);
            unsigned int v0 = r0[l];
            a0 += al0 * bf2f((unsigned short)(v0 & 0xffff));
            a1 += al0 * bf2f((unsigned short)(v0 >> 16));
        }
        __syncthreads();
    }
    red[w][l * 2 + 0] = a0;
    red[w][l * 2 + 1] = a1;
    __syncthreads();
    if (tid < HID2) {
        float r = red[0][tid] + red[1][tid] + red[2][tid] + red[3][tid] + b2[tid];
        r = (r > 0.f) ? r : 0.f;  // ReLU
        x2bf[(size_t)n * HID2 + tid] = __float2bfloat16(r);
    }
}

// ---------------- host launch ----------------

extern "C" void kernel_launch(void* const* d_in, const int* in_sizes, int n_in,
                              void* d_out, int out_size, void* d_ws, size_t ws_size,
                              hipStream_t stream) {
    (void)in_sizes; (void)n_in; (void)out_size; (void)ws_size;
    const float* x        = (const float*)d_in[0];
    const int*   eindex   = (const int*)d_in[1];
    const float* W1       = (const float*)d_in[2];
    const float* att_src1 = (const float*)d_in[3];
    const float* att_dst1 = (const float*)d_in[4];
    const float* b1       = (const float*)d_in[5];
    const float* W2       = (const float*)d_in[6];
    const float* att_src2 = (const float*)d_in[7];
    const float* att_dst2 = (const float*)d_in[8];
    const float* b2       = (const float*)d_in[9];
    const float* fcW1     = (const float*)d_in[10];
    const float* fcb1     = (const float*)d_in[11];
    const float* fcW2     = (const float*)d_in[12];
    const float* fcb2     = (const float*)d_in[13];

    const int* src = eindex;
    const int* dst = eindex + EE;

    float* out_n      = (float*)d_out;               // [N]
    float* alpha1_out = out_n + NN;                  // [E,8]
    float* alpha2_out = alpha1_out + (size_t)EE * 8; // [E]

    char* ws = (char*)d_ws;
    size_t off = 0;
    auto alloc = [&](size_t bytes) {
        size_t o = off;
        off = (off + bytes + 255) & ~(size_t)255;
        return o;
    };
    size_t o_rowptr = alloc((NN + 1) * sizeof(int));
    size_t o_cursor = alloc(NN * sizeof(int));
    size_t o_counts = alloc(NN * sizeof(int));
    size_t o_excl   = alloc(NN * sizeof(int));
    size_t o_bsum   = alloc(64 * sizeof(int));
    size_t o_eidx   = alloc(EE * sizeof(int));
    size_t o_srcs   = alloc(EE * sizeof(int));
    size_t o_h1     = alloc((size_t)NN * HID1 * sizeof(float));
    size_t o_e1s    = alloc((size_t)EE * H1 * sizeof(float));
    size_t o_as1    = alloc((size_t)NN * H1 * sizeof(float));
    size_t o_ad1    = alloc((size_t)NN * H1 * sizeof(float));
    size_t o_h1bf   = alloc((size_t)NN * HID1 * sizeof(__hip_bfloat16));
    size_t o_xbf    = alloc((size_t)NN * IN_DIM * sizeof(__hip_bfloat16));
    size_t o_x1bf   = alloc((size_t)NN * HID1 * sizeof(__hip_bfloat16));
    size_t o_x2bf   = alloc((size_t)NN * HID2 * sizeof(__hip_bfloat16));
    size_t o_W1p    = alloc((size_t)IN_DIM * HID1 * sizeof(__hip_bfloat16));
    size_t o_W2p    = alloc((size_t)HID1 * HID2 * sizeof(__hip_bfloat16));
    size_t o_fW1p   = alloc((size_t)HID2 * FC1 * sizeof(__hip_bfloat16));

    int*   row_ptr = (int*)(ws + o_rowptr);
    int*   cursor  = (int*)(ws + o_cursor);
    int*   counts  = (int*)(ws + o_counts);
    int*   excl    = (int*)(ws + o_excl);
    int*   bsum    = (int*)(ws + o_bsum);
    int*   eidx    = (int*)(ws + o_eidx);
    int*   srcs    = (int*)(ws + o_srcs);
    float* h1      = (float*)(ws + o_h1);
    float* e1s     = (float*)(ws + o_e1s);
    float* a_s1    = (float*)(ws + o_as1);
    float* a_d1    = (float*)(ws + o_ad1);
    __hip_bfloat16* h1bf  = (__hip_bfloat16*)(ws + o_h1bf);
    __hip_bfloat16* xbf   = (__hip_bfloat16*)(ws + o_xbf);
    __hip_bfloat16* x1bf  = (__hip_bfloat16*)(ws + o_x1bf);
    __hip_bfloat16* x2bf  = (__hip_bfloat16*)(ws + o_x2bf);
    __hip_bfloat16* W1p   = (__hip_bfloat16*)(ws + o_W1p);
    __hip_bfloat16* W2p   = (__hip_bfloat16*)(ws + o_W2p);
    __hip_bfloat16* fW1p  = (__hip_bfloat16*)(ws + o_fW1p);
    // layer-2 aliases
    float* h2   = h1;
    float* e2s  = e1s;
    float* a_s2 = a_s1;
    float* a_d2 = a_d1;
    __hip_bfloat16* h2bf = h1bf;

    const int SCAN_NB = (NN + 1023) / 1024;  // 49

    // ---- build CSR by dst ----
    fill_zero_int<<<(NN + 255) / 256, 256, 0, stream>>>(counts, NN);
    hist_kernel<<<(EE + 255) / 256, 256, 0, stream>>>(dst, counts);
    scan_a_kernel<<<SCAN_NB, 256, 0, stream>>>(counts, excl, bsum, NN);
    scan_b_kernel<<<1, 64, 0, stream>>>(bsum, row_ptr, SCAN_NB, NN);
    scan_c_kernel<<<SCAN_NB, 256, 0, stream>>>(excl, bsum, row_ptr, cursor, NN);
    scatter_kernel<<<(EE + 255) / 256, 256, 0, stream>>>(src, dst, cursor, eidx, srcs);

    // ---- input conversions / weight packing ----
    cvt_bf16_kernel<<<(NN * IN_DIM + 255) / 256, 256, 0, stream>>>(x, xbf, NN * IN_DIM);
    pack_kernel<<<(IN_DIM * HID1 + 255) / 256, 256, 0, stream>>>(W1, W1p, IN_DIM, HID1);
    pack_kernel<<<(HID1 * HID2 + 255) / 256, 256, 0, stream>>>(W2, W2p, HID1, HID2);
    pack_kernel<<<(HID2 * FC1 + 255) / 256, 256, 0, stream>>>(fcW1, fW1p, HID2, FC1);

    // ---- layer 1 ----
    mgemm_kernel<<<dim3((NN + 127) / 128, HID1 / 64), 256, 0, stream>>>(
        xbf, W1p, h1, h1bf, NN, IN_DIM, HID1);
    att1_kernel<<<(NN * H1 + 255) / 256, 256, 0, stream>>>(h1, att_src1, att_dst1, a_s1, a_d1);
    edge_e1_kernel<<<(EE + 255) / 256, 256, 0, stream>>>(eidx, srcs, dst, a_s1, a_d1, e1s);
    softmax1_kernel<<<(NN + 3) / 4, 256, 0, stream>>>(row_ptr, eidx, e1s, alpha1_out);
    agg1_kernel<<<NN, 256, 0, stream>>>(row_ptr, srcs, e1s, h1bf, b1, x1bf);

    // ---- layer 2 ----
    mgemm_kernel<<<dim3((NN + 127) / 128, HID2 / 64), 256, 0, stream>>>(
        x1bf, W2p, h2, h2bf, NN, HID1, HID2);
    att2_kernel<<<NN, 64, 0, stream>>>(h2, att_src2, att_dst2, a_s2, a_d2);
    edge_e2_kernel<<<(EE + 255) / 256, 256, 0, stream>>>(eidx, srcs, dst, a_s2, a_d2, e2s);
    softmax2_kernel<<<(NN + 3) / 4, 256, 0, stream>>>(row_ptr, eidx, e2s, alpha2_out);
    agg2_kernel<<<NN, 256, 0, stream>>>(row_ptr, srcs, e2s, h2bf, b2, x2bf);

    // ---- FC head ----
    fc_mfma_kernel<<<(NN + 31) / 32, 256, 0, stream>>>(x2bf, fW1p, fcb1, fcW2, fcb2, out_n);
}